// Round 17
// baseline (237.478 us; speedup 1.0000x reference)
//
#include <hip/hip_runtime.h>
#include <math.h>

// Hardened single-rounded ops (never contracted/fused by the compiler):
#define FMUL(a,b) __fmul_rn((a),(b))
#define FADD(a,b) __fadd_rn((a),(b))
#define FSUB(a,b) __fsub_rn((a),(b))

#define BB 2048   // batch
#define DD 1024   // feature dim (K)
#define TT 32     // LIF steps
#define TS 64     // output tile per block
#define KB 16     // K slab per LDS stage
#define LDW 20    // padded LDS row (floats); 80B stride, 2-way conflicts only (free)

// CONFIRMED golden semantics (r16 band 7, zero flips in 8.4M knife-edge cmps):
//   dot  = FADD( fmaf-chain(k=0..511), fmaf-chain(k=512..1023) )   [BLIS KC=512]
//   cur  = FADD(dot, bias[e])
//   rec  : m = FSUB(FADD(FMUL(0.9f, m), cur), reset), spike = (m > 1.0f)
// Output: updated [B*D] | spikes [B*T*D] | scale [1]
__global__ __launch_bounds__(256) void lif_fused_kernel(
    const float* __restrict__ latent,
    const float* __restrict__ W,
    const float* __restrict__ bias,
    const float* __restrict__ gainp,
    float* __restrict__ out)
{
    __shared__ __align__(16) float As[TS][LDW];
    __shared__ __align__(16) float Ws[TS][LDW];

    const int tid = threadIdx.x;
    const int tx = tid & 15;        // 4 output cols each
    const int ty = tid >> 4;        // 4 output rows each
    const int e0 = blockIdx.x * TS;
    const int b0 = blockIdx.y * TS;

    const int lrow = tid >> 2;      // 0..63
    const int lf4  = tid & 3;       // which float4 of the 16-wide k slab

    const float* aptr = latent + (size_t)(b0 + lrow) * DD + lf4 * 4;
    const float* wptr = W      + (size_t)(e0 + lrow) * DD + lf4 * 4;

    float tot[4][4];
    float acc[4][4];

    // two KC=512 chunks: slabs [0,32) and [32,64)
    for (int c = 0; c < 2; ++c) {
        const int sBeg = c * 32;
        const int sEnd = sBeg + 32;

#pragma unroll
        for (int i = 0; i < 4; ++i)
#pragma unroll
            for (int j = 0; j < 4; ++j) acc[i][j] = 0.0f;

        for (int s = sBeg; s < sEnd; ++s) {
            const int k0 = s * KB;
            float4 av = *(const float4*)(aptr + k0);
            float4 wv = *(const float4*)(wptr + k0);
            __syncthreads();  // previous slab fully consumed
            *(float4*)&As[lrow][lf4 * 4] = av;
            *(float4*)&Ws[lrow][lf4 * 4] = wv;
            __syncthreads();

            float4 A4[4][4];
#pragma unroll
            for (int i = 0; i < 4; ++i)
#pragma unroll
                for (int sub = 0; sub < 4; ++sub)
                    A4[i][sub] = *(const float4*)&As[ty * 4 + i][sub * 4];

#pragma unroll
            for (int j = 0; j < 4; ++j) {
                float4 W4[4];
#pragma unroll
                for (int sub = 0; sub < 4; ++sub)
                    W4[sub] = *(const float4*)&Ws[tx * 4 + j][sub * 4];
#pragma unroll
                for (int i = 0; i < 4; ++i) {
                    float a = acc[i][j];
                    // strict ascending k within slab: k = k0 + sub*4 + L
#pragma unroll
                    for (int sub = 0; sub < 4; ++sub) {
                        float4 av4 = A4[i][sub];
                        float4 wv4 = W4[sub];
                        a = fmaf(av4.x, wv4.x, a);
                        a = fmaf(av4.y, wv4.y, a);
                        a = fmaf(av4.z, wv4.z, a);
                        a = fmaf(av4.w, wv4.w, a);
                    }
                    acc[i][j] = a;
                }
            }
        }

#pragma unroll
        for (int i = 0; i < 4; ++i)
#pragma unroll
            for (int j = 0; j < 4; ++j)
                tot[i][j] = (c == 0) ? acc[i][j] : FADD(tot[i][j], acc[i][j]);
    }

    // cur = FADD(dot, bias)
    float4 bv = *(const float4*)&bias[e0 + tx * 4];
    float cur[4][4];
#pragma unroll
    for (int i = 0; i < 4; ++i) {
        cur[i][0] = FADD(tot[i][0], bv.x);
        cur[i][1] = FADD(tot[i][1], bv.y);
        cur[i][2] = FADD(tot[i][2], bv.z);
        cur[i][3] = FADD(tot[i][3], bv.w);
    }

    // hardened f32 LIF recurrence
    float mem[4][4];
    int cnt[4][4];
#pragma unroll
    for (int i = 0; i < 4; ++i)
#pragma unroll
        for (int j = 0; j < 4; ++j) { mem[i][j] = 0.0f; cnt[i][j] = 0; }

    float* spk_base = out + (size_t)BB * DD;
    const int colf = e0 + tx * 4;

    for (int t = 0; t < TT; ++t) {
#pragma unroll
        for (int i = 0; i < 4; ++i) {
            const int row = b0 + ty * 4 + i;
            float4 s;
#pragma unroll
            for (int j = 0; j < 4; ++j) {
                float m = mem[i][j];
                float r = (m > 1.0f) ? 1.0f : 0.0f;
                m = FSUB(FADD(FMUL(0.9f, m), cur[i][j]), r);
                mem[i][j] = m;
                int fired = (m > 1.0f) ? 1 : 0;
                cnt[i][j] += fired;
                ((float*)&s)[j] = (float)fired;
            }
            *(float4*)&spk_base[(size_t)row * TT * DD + (size_t)t * DD + colf] = s;
        }
    }

    // scale = 0.4*sigmoid(gain); updated = relu(latent + scale*mean_t(spikes))
    const float g = gainp[0];
    const float scale = 0.4f * (1.0f / (1.0f + expf(-g)));

#pragma unroll
    for (int i = 0; i < 4; ++i) {
        const int row = b0 + ty * 4 + i;
        float4 lv = *(const float4*)&latent[(size_t)row * DD + colf];
        float4 u;
#pragma unroll
        for (int j = 0; j < 4; ++j) {
            float mean = (float)cnt[i][j] * 0.03125f;   // exact (pow2)
            float tterm = FMUL(scale, mean);
            float v = FADD(((const float*)&lv)[j], tterm);
            ((float*)&u)[j] = v > 0.0f ? v : 0.0f;
        }
        *(float4*)&out[(size_t)row * DD + colf] = u;
    }

    if (blockIdx.x == 0 && blockIdx.y == 0 && tid == 0) {
        out[(size_t)BB * DD + (size_t)BB * TT * DD] = scale;
    }
}

extern "C" void kernel_launch(void* const* d_in, const int* in_sizes, int n_in,
                              void* d_out, int out_size, void* d_ws, size_t ws_size,
                              hipStream_t stream) {
    (void)in_sizes; (void)n_in; (void)d_ws; (void)ws_size; (void)out_size;
    const float* latent = (const float*)d_in[0];
    const float* W      = (const float*)d_in[1];
    const float* bias   = (const float*)d_in[2];
    const float* gain   = (const float*)d_in[3];
    float* out = (float*)d_out;

    dim3 grid(DD / TS, BB / TS);  // (16, 32)
    dim3 block(256);
    lif_fused_kernel<<<grid, block, 0, stream>>>(latent, W, bias, gain, out);
}

// Round 18
// 125.016 us; speedup vs baseline: 1.8996x; 1.8996x over previous
//
#include <hip/hip_runtime.h>
#include <math.h>

// Hardened single-rounded ops (never contracted/fused by the compiler):
#define FMUL(a,b) __fmul_rn((a),(b))
#define FADD(a,b) __fadd_rn((a),(b))
#define FSUB(a,b) __fsub_rn((a),(b))

#define BB 2048   // batch
#define DD 1024   // feature dim (K)
#define TT 32     // LIF steps
#define TS 64     // output tile per block
#define KB 32     // K slab per LDS stage (8 float4 subs)
#define NSLAB (DD / KB)        // 32
#define HALF  (NSLAB / 2)      // chunk boundary slab (k=512)

// CONFIRMED golden semantics (r16 band 7, bit-exact):
//   dot = FADD( fmaf-chain(k=0..511), fmaf-chain(k=512..1023) )
//   cur = FADD(dot, bias[e]); rec: m = FSUB(FADD(FMUL(0.9f,m),cur),reset)
// Output: updated [B*D] | spikes [B*T*D] | scale [1]
__global__ __launch_bounds__(256) void lif_fused_kernel(
    const float* __restrict__ latent,
    const float* __restrict__ W,
    const float* __restrict__ bias,
    const float* __restrict__ gainp,
    float* __restrict__ out)
{
    // Conflict-free layout: [buf][sub][row] of float4. Reads:
    //   As4[p][sub][ty*4+i]: 16 lanes same addr (broadcast) x 4 addrs, 2-way max.
    //   Ws4[p][sub][tx*4+j]: banks 16*tx+4j+w -> tx,tx+2 collide = 2-way (free).
    // Writes As4[p][lf4][lrow]: banks lrow*4+w -> lrow,lrow+8 collide = 2-way.
    __shared__ float4 As4[2][KB / 4][TS];
    __shared__ float4 Ws4[2][KB / 4][TS];

    const int tid = threadIdx.x;
    const int tx = tid & 15;        // 4 output cols each
    const int ty = tid >> 4;        // 4 output rows each
    const int e0 = blockIdx.x * TS;
    const int b0 = blockIdx.y * TS;

    const int lrow = tid >> 2;      // 0..63 (staging row)
    const int lf4  = tid & 3;       // which float4 within first 16 of the slab

    const float* aptr = latent + (size_t)(b0 + lrow) * DD + lf4 * 4;
    const float* wptr = W      + (size_t)(e0 + lrow) * DD + lf4 * 4;

    float tot[4][4];
    float acc[4][4];
#pragma unroll
    for (int i = 0; i < 4; ++i)
#pragma unroll
        for (int j = 0; j < 4; ++j) acc[i][j] = 0.0f;

    // prologue: slab 0 into regs
    float4 a0 = *(const float4*)(aptr +  0);
    float4 a1 = *(const float4*)(aptr + 16);
    float4 w0 = *(const float4*)(wptr +  0);
    float4 w1 = *(const float4*)(wptr + 16);

    int p = 0;
    for (int s = 0; s < NSLAB; ++s) {
        As4[p][lf4    ][lrow] = a0;
        As4[p][lf4 + 4][lrow] = a1;
        Ws4[p][lf4    ][lrow] = w0;
        Ws4[p][lf4 + 4][lrow] = w1;
        __syncthreads();

        if (s + 1 < NSLAB) {   // prefetch next slab (overlaps with compute below)
            const int k0 = (s + 1) * KB;
            a0 = *(const float4*)(aptr + k0);
            a1 = *(const float4*)(aptr + k0 + 16);
            w0 = *(const float4*)(wptr + k0);
            w1 = *(const float4*)(wptr + k0 + 16);
        }

        if (s == HALF) {   // chunk boundary k=512: save chunk1, restart chain
#pragma unroll
            for (int i = 0; i < 4; ++i)
#pragma unroll
                for (int j = 0; j < 4; ++j) { tot[i][j] = acc[i][j]; acc[i][j] = 0.0f; }
        }

#pragma unroll
        for (int sub = 0; sub < KB / 4; ++sub) {
            float4 a4[4], w4[4];
#pragma unroll
            for (int i = 0; i < 4; ++i) a4[i] = As4[p][sub][ty * 4 + i];
#pragma unroll
            for (int j = 0; j < 4; ++j) w4[j] = Ws4[p][sub][tx * 4 + j];
#pragma unroll
            for (int j = 0; j < 4; ++j)
#pragma unroll
                for (int i = 0; i < 4; ++i) {
                    float a = acc[i][j];
                    a = fmaf(a4[i].x, w4[j].x, a);
                    a = fmaf(a4[i].y, w4[j].y, a);
                    a = fmaf(a4[i].z, w4[j].z, a);
                    a = fmaf(a4[i].w, w4[j].w, a);
                    acc[i][j] = a;
                }
        }
        p ^= 1;
    }

    // dot = FADD(chunk1, chunk2); cur = FADD(dot, bias)
    float4 bv = *(const float4*)&bias[e0 + tx * 4];
    float cur[4][4];
#pragma unroll
    for (int i = 0; i < 4; ++i) {
        cur[i][0] = FADD(FADD(tot[i][0], acc[i][0]), bv.x);
        cur[i][1] = FADD(FADD(tot[i][1], acc[i][1]), bv.y);
        cur[i][2] = FADD(FADD(tot[i][2], acc[i][2]), bv.z);
        cur[i][3] = FADD(FADD(tot[i][3], acc[i][3]), bv.w);
    }

    // hardened f32 LIF recurrence
    float mem[4][4];
    int cnt[4][4];
#pragma unroll
    for (int i = 0; i < 4; ++i)
#pragma unroll
        for (int j = 0; j < 4; ++j) { mem[i][j] = 0.0f; cnt[i][j] = 0; }

    float* spk_base = out + (size_t)BB * DD;
    const int colf = e0 + tx * 4;

    for (int t = 0; t < TT; ++t) {
#pragma unroll
        for (int i = 0; i < 4; ++i) {
            const int row = b0 + ty * 4 + i;
            float4 s;
#pragma unroll
            for (int j = 0; j < 4; ++j) {
                float m = mem[i][j];
                float r = (m > 1.0f) ? 1.0f : 0.0f;
                m = FSUB(FADD(FMUL(0.9f, m), cur[i][j]), r);
                mem[i][j] = m;
                int fired = (m > 1.0f) ? 1 : 0;
                cnt[i][j] += fired;
                ((float*)&s)[j] = (float)fired;
            }
            *(float4*)&spk_base[(size_t)row * TT * DD + (size_t)t * DD + colf] = s;
        }
    }

    // scale = 0.4*sigmoid(gain); updated = relu(latent + scale*mean_t(spikes))
    const float g = gainp[0];
    const float scale = 0.4f * (1.0f / (1.0f + expf(-g)));

#pragma unroll
    for (int i = 0; i < 4; ++i) {
        const int row = b0 + ty * 4 + i;
        float4 lv = *(const float4*)&latent[(size_t)row * DD + colf];
        float4 u;
#pragma unroll
        for (int j = 0; j < 4; ++j) {
            float mean = (float)cnt[i][j] * 0.03125f;   // exact (pow2)
            float tterm = FMUL(scale, mean);
            float v = FADD(((const float*)&lv)[j], tterm);
            ((float*)&u)[j] = v > 0.0f ? v : 0.0f;
        }
        *(float4*)&out[(size_t)row * DD + colf] = u;
    }

    if (blockIdx.x == 0 && blockIdx.y == 0 && tid == 0) {
        out[(size_t)BB * DD + (size_t)BB * TT * DD] = scale;
    }
}

extern "C" void kernel_launch(void* const* d_in, const int* in_sizes, int n_in,
                              void* d_out, int out_size, void* d_ws, size_t ws_size,
                              hipStream_t stream) {
    (void)in_sizes; (void)n_in; (void)d_ws; (void)ws_size; (void)out_size;
    const float* latent = (const float*)d_in[0];
    const float* W      = (const float*)d_in[1];
    const float* bias   = (const float*)d_in[2];
    const float* gain   = (const float*)d_in[3];
    float* out = (float*)d_out;

    dim3 grid(DD / TS, BB / TS);  // (16, 32) = 512 blocks
    dim3 block(256);
    lif_fused_kernel<<<grid, block, 0, stream>>>(latent, W, bias, gain, out);
}